// Round 18
// baseline (410.850 us; speedup 1.0000x reference)
//
#include <hip/hip_runtime.h>
#include <math.h>

typedef unsigned short u16;
typedef unsigned int u32;
typedef __attribute__((ext_vector_type(8))) short short8;
typedef __attribute__((ext_vector_type(2))) unsigned int u32x2;
typedef __attribute__((ext_vector_type(4))) float f32x4;

static __device__ __forceinline__ u16 f2bf(float f) {
    union { float f; unsigned int u; } c; c.f = f;
    unsigned int u = c.u;
    u += 0x7FFF + ((u >> 16) & 1);
    return (u16)(u >> 16);
}
static __device__ __forceinline__ float bf2f(u16 u) {
    union { unsigned int i; float f; } c; c.i = ((unsigned int)u) << 16;
    return c.f;
}
// pack two f32 -> two bf16 in one VALU op
static __device__ __forceinline__ u32 pk2bf(float lo, float hi) {
    u32 r;
    asm("v_cvt_pk_bf16_f32 %0, %1, %2" : "=v"(r) : "v"(lo), "v"(hi));
    return r;
}
// tanh-form GELU via sigmoid
static __device__ __forceinline__ float gelu_f(float v) {
    float y = 0.7978845608f * (v + 0.044715f * v * v * v);
    return v / (1.0f + __expf(-2.0f * y));
}

#define GLOAD16(g, s) __builtin_amdgcn_global_load_lds( \
    (const __attribute__((address_space(1))) void*)(g), \
    (__attribute__((address_space(3))) void*)(s), 16, 0, 0)

// ---------------- merged prep ----------------
struct PrepArgs {
    const float* src[11];
    u16* dst[11];
    int K[11];
    int N[11];
    int end[11];
    int cnt;
};

__global__ void k_prep(PrepArgs a)
{
    __shared__ float tile[32][33];
    const int bid = blockIdx.x;
    int e = 0;
    while (e < a.cnt - 1 && bid >= a.end[e]) e++;
    const int local = bid - (e ? a.end[e - 1] : 0);
    const float* __restrict__ src = a.src[e];
    u16* __restrict__ dst = a.dst[e];
    const int K = a.K[e], N = a.N[e];
    const int tx = threadIdx.x, ty = threadIdx.y;

    if (K == 0) {
        size_t base = (size_t)local * 2048 + (size_t)(ty * 32 + tx) * 8;
        float4 v0 = *(const float4*)(src + base);
        float4 v1 = *(const float4*)(src + base + 4);
        short8 o;
        o[0] = (short)f2bf(v0.x); o[1] = (short)f2bf(v0.y);
        o[2] = (short)f2bf(v0.z); o[3] = (short)f2bf(v0.w);
        o[4] = (short)f2bf(v1.x); o[5] = (short)f2bf(v1.y);
        o[6] = (short)f2bf(v1.z); o[7] = (short)f2bf(v1.w);
        *(short8*)&dst[base] = o;
        return;
    }
    const int nbx = N / 32;
    const int bx = local % nbx, by = local / nbx;
    const int n0 = bx * 32, k0 = by * 32;
#pragma unroll
    for (int i = 0; i < 4; i++)
        tile[ty + i * 8][tx] = src[(size_t)(k0 + ty + i * 8) * N + n0 + tx];
    __syncthreads();
#pragma unroll
    for (int i = 0; i < 4; i++)
        dst[(size_t)(n0 + ty + i * 8) * K + k0 + tx] = f2bf(tile[tx][ty + i * 8]);
}

// ---------------- LayerNorm over 768 ----------------
__global__ __launch_bounds__(256) void k_layernorm(
    const float* __restrict__ x, const float* __restrict__ g, const float* __restrict__ b,
    float* __restrict__ outF, u16* __restrict__ outB)
{
    const int row = blockIdx.x, t = threadIdx.x;
    const float* xr = x + (size_t)row * 768;
    float v[3];
#pragma unroll
    for (int i = 0; i < 3; i++) v[i] = xr[t + i * 256];
    __shared__ float sred[4];
    float s = v[0] + v[1] + v[2];
#pragma unroll
    for (int o = 32; o; o >>= 1) s += __shfl_xor(s, o, 64);
    if ((t & 63) == 0) sred[t >> 6] = s;
    __syncthreads();
    float mu = (sred[0] + sred[1] + sred[2] + sred[3]) * (1.0f / 768.0f);
    __syncthreads();
    float q = 0.f;
#pragma unroll
    for (int i = 0; i < 3; i++) { float d = v[i] - mu; q += d * d; }
#pragma unroll
    for (int o = 32; o; o >>= 1) q += __shfl_xor(q, o, 64);
    if ((t & 63) == 0) sred[t >> 6] = q;
    __syncthreads();
    float var = (sred[0] + sred[1] + sred[2] + sred[3]) * (1.0f / 768.0f);
    float rstd = rsqrtf(var + 1e-5f);
#pragma unroll
    for (int i = 0; i < 3; i++) {
        int c = t + i * 256;
        float y = (v[i] - mu) * rstd * g[c] + b[c];
        if (outF) outF[(size_t)row * 768 + c] = y;
        if (outB) outB[(size_t)row * 768 + c] = f2bf(y);
    }
}

// ---------------- GEMM: BM=128, BK=64, both-sides XOR swizzle, XCD swizzle ----------------
// BN=192: 4 waves, wave tile 64x96 (acc[4][6]) — 1.2x lower LDS bytes/MFMA.
// BN=64:  4 waves, wave tile 32x64 (acc[2][4]) — for skinny N (grid occupancy).
template<int BN>
__global__ __launch_bounds__(256) void k_gemm(
    const u16* __restrict__ A, const u16* __restrict__ Bt,
    const float* __restrict__ b1, const float* __restrict__ b2, const float* __restrict__ b3,
    const float* __restrict__ resid, const u16* __restrict__ residB,
    float* __restrict__ outF, u16* __restrict__ outB, u16* __restrict__ outK, u16* __restrict__ outV,
    int M, int N, int K, int do_gelu, int mode, int vT_log)
{
    constexpr int MR = (BN == 64) ? 2 : 4;
    constexpr int NR = (BN == 192) ? 6 : 4;
    __shared__ u16 As[128 * 64];
    __shared__ u16 Bs[BN * 64];
    const int t = threadIdx.x;
    const int w = t >> 6, l = t & 63;
    const int lr = l & 15, lg = l >> 4;

    const unsigned nwg = gridDim.x * gridDim.y;
    unsigned bid = blockIdx.y * gridDim.x + blockIdx.x;
    bid = (bid & 7) * (nwg >> 3) + (bid >> 3);
    const int m0 = (bid / gridDim.x) * 128, n0 = (bid % gridDim.x) * BN;

    const int wr = (BN == 64) ? (w * 32) : ((w >> 1) * 64);
    const int wc = (BN == 192) ? ((w & 1) * 96) : 0;

    const int srow = t >> 3;            // 0..31
    const int sslot = t & 7;            // 16B slot within 128B row

    f32x4 acc[MR][NR] = {};

    for (int k0 = 0; k0 < K; k0 += 64) {
        __syncthreads();
#pragma unroll
        for (int i = 0; i < 4; i++) {
            int row = i * 32 + srow;
            GLOAD16(A + (size_t)(m0 + row) * K + k0 + ((sslot ^ (row & 7)) * 8),
                    &As[i * 2048 + w * 512]);
        }
#pragma unroll
        for (int i = 0; i < BN / 32; i++) {
            int row = i * 32 + srow;
            GLOAD16(Bt + (size_t)(n0 + row) * K + k0 + ((sslot ^ (row & 7)) * 8),
                    &Bs[i * 2048 + w * 512]);
        }
        __syncthreads();
#pragma unroll
        for (int kk = 0; kk < 2; kk++) {
            const int ce = kk * 32 + lg * 8;
            short8 af[MR], bfr[NR];
#pragma unroll
            for (int m = 0; m < MR; m++) {
                int row = wr + m * 16 + lr;
                af[m] = *(const short8*)&As[row * 64 + (ce ^ ((row & 7) << 3))];
            }
#pragma unroll
            for (int n = 0; n < NR; n++) {
                int row = wc + n * 16 + lr;
                bfr[n] = *(const short8*)&Bs[row * 64 + (ce ^ ((row & 7) << 3))];
            }
#pragma unroll
            for (int m = 0; m < MR; m++)
#pragma unroll
                for (int n = 0; n < NR; n++)
                    acc[m][n] = __builtin_amdgcn_mfma_f32_16x16x32_bf16(af[m], bfr[n], acc[m][n], 0, 0, 0);
        }
    }

#pragma unroll
    for (int m = 0; m < MR; m++) {
        int row0 = m0 + wr + m * 16 + lg * 4;
#pragma unroll
        for (int n = 0; n < NR; n++) {
            int col = n0 + wc + n * 16 + lr;
            const float* bp = b1; int lc = col; u16* tgt = outB; int vT = 0;
            if (mode == 2) {
                if (col >= 1536)     { bp = b3; lc = col - 1536; tgt = outV; vT = 1; }
                else if (col >= 768) { bp = b2; lc = col - 768;  tgt = outK; }
            } else if (mode == 3) {
                if (col >= 768)      { bp = b3; lc = col - 768;  tgt = outV; vT = 1; }
            }
            float bv = bp[lc];
            float vv[4];
#pragma unroll
            for (int j = 0; j < 4; j++) {
                float v = acc[m][n][j] + bv;
                if (do_gelu) v = gelu_f(v);
                vv[j] = v;
            }
            if (mode == 0) {
#pragma unroll
                for (int j = 0; j < 4; j++) {
                    size_t idx = (size_t)(row0 + j) * N + col;
                    float v = vv[j];
                    if (resid)  v += resid[idx];
                    if (residB) v += bf2f(residB[idx]);
                    if (outF) outF[idx] = v;
                    if (outB) outB[idx] = f2bf(v);
                }
            } else if (!vT) {
#pragma unroll
                for (int j = 0; j < 4; j++)
                    tgt[(size_t)(row0 + j) * 768 + lc] = f2bf(vv[j]);
            } else {
                int head = lc >> 6, d = lc & 63;
                int bq = row0 >> vT_log, s = row0 & ((1 << vT_log) - 1);
                u32x2 pk;
                pk[0] = pk2bf(vv[0], vv[1]);
                pk[1] = pk2bf(vv[2], vv[3]);
                *(u32x2*)&tgt[((size_t)((bq * 12 + head) * 64 + d) << vT_log) + s] = pk;
            }
        }
    }
}

// ---------------- Flash attention: QBLK=64 (4 waves x 16 q-rows), swapped-operand ----------------
template<bool CAUSAL>
__global__ __launch_bounds__(256) void k_attn(
    const u16* __restrict__ Q, const u16* __restrict__ K,
    const u16* __restrict__ Vt, u16* __restrict__ Y,
    int Tq, int Skv)
{
    const int bh = blockIdx.x;
    const int b = bh / 12, h = bh % 12;
    const int qt = CAUSAL ? ((int)gridDim.y - 1 - (int)blockIdx.y) : blockIdx.y;
    const int q0 = qt * 64;
    const int t = threadIdx.x, w = t >> 6, l = t & 63;
    const int lr = l & 15, lg = l >> 4;
    const int swz = (lr & 7) << 3;
    const float QSC = 0.125f * 1.44269504088896f;

    const u16* Qb = Q + (size_t)b * Tq * 768 + h * 64;
    const u16* Kb = K + (size_t)b * Skv * 768 + h * 64;
    const u16* Vb = Vt + (size_t)bh * 64 * Skv;

    __shared__ u16 Ks[2][64 * 64];
    __shared__ u16 Vs[2][64 * 64];
    __shared__ u16 Ps[4][16 * 64];

    short8 aq[2];
    {
        const u16* qr = Qb + (size_t)(q0 + w * 16 + lr) * 768 + lg * 8;
#pragma unroll
        for (int hh = 0; hh < 2; hh++) {
            short8 raw = *(const short8*)(qr + hh * 32);
            union { short8 s; u32 u[4]; } cv;
#pragma unroll
            for (int i = 0; i < 4; i++)
                cv.u[i] = pk2bf(bf2f((u16)raw[2 * i]) * QSC, bf2f((u16)raw[2 * i + 1]) * QSC);
            aq[hh] = cv.s;
        }
    }

    f32x4 acc[4] = {};
    float mrun = -INFINITY;
    float lrun = 0.f;

    const int nt = CAUSAL ? (qt + 1) : (Skv / 64);

    const int r0 = t >> 3, r1 = 32 + (t >> 3);
    const int db = (t & 7) * 8;
    const int sw0 = db ^ ((r0 & 7) << 3);
    const int sw1 = db ^ ((r1 & 7) << 3);

    short8 kr0, kr1, vr0, vr1;
    kr0 = *(const short8*)(Kb + (size_t)r0 * 768 + db);
    kr1 = *(const short8*)(Kb + (size_t)r1 * 768 + db);
    vr0 = *(const short8*)(Vb + (size_t)r0 * Skv + db);
    vr1 = *(const short8*)(Vb + (size_t)r1 * Skv + db);
    *(short8*)&Ks[0][r0 * 64 + sw0] = kr0;
    *(short8*)&Ks[0][r1 * 64 + sw1] = kr1;
    *(short8*)&Vs[0][r0 * 64 + sw0] = vr0;
    *(short8*)&Vs[0][r1 * 64 + sw1] = vr1;
    __syncthreads();
    int cur = 0;

    for (int kt = 0; kt < nt; kt++) {
        const int kv0 = kt * 64;
        const bool more = (kt + 1 < nt);
        if (more) {
            const int kn = kv0 + 64;
            kr0 = *(const short8*)(Kb + (size_t)(kn + r0) * 768 + db);
            kr1 = *(const short8*)(Kb + (size_t)(kn + r1) * 768 + db);
            vr0 = *(const short8*)(Vb + (size_t)r0 * Skv + kn + db);
            vr1 = *(const short8*)(Vb + (size_t)r1 * Skv + kn + db);
        }

        const u16* KsC = Ks[cur];
        f32x4 st[4];
        __builtin_amdgcn_s_setprio(1);
#pragma unroll
        for (int c = 0; c < 4; c++) {
            const short8 kb0 = *(const short8*)&KsC[(c * 16 + lr) * 64 + ((lg * 8) ^ swz)];
            const short8 kb1 = *(const short8*)&KsC[(c * 16 + lr) * 64 + ((32 | (lg * 8)) ^ swz)];
            f32x4 a = {};
            a = __builtin_amdgcn_mfma_f32_16x16x32_bf16(kb0, aq[0], a, 0, 0, 0);
            a = __builtin_amdgcn_mfma_f32_16x16x32_bf16(kb1, aq[1], a, 0, 0, 0);
            st[c] = a;
        }
        __builtin_amdgcn_s_setprio(0);

        if (CAUSAL && kt == nt - 1) {
            int qv = q0 + w * 16 + lr;
#pragma unroll
            for (int c = 0; c < 4; c++)
#pragma unroll
                for (int j = 0; j < 4; j++) {
                    int kvv = kv0 + c * 16 + lg * 4 + j;
                    if (kvv > qv) st[c][j] = -1e30f;
                }
        }

        float mc[4];
#pragma unroll
        for (int c = 0; c < 4; c++)
            mc[c] = fmaxf(fmaxf(st[c][0], st[c][1]), fmaxf(st[c][2], st[c][3]));
        float lmax = fmaxf(fmaxf(mc[0], mc[1]), fmaxf(mc[2], mc[3]));
        if (!__all(lmax - mrun <= 8.0f)) {
            float m = lmax;
            m = fmaxf(m, __shfl_xor(m, 16, 64));
            m = fmaxf(m, __shfl_xor(m, 32, 64));
            float mnew = fmaxf(mrun, m);
            float sc = exp2f(mrun - mnew);
            mrun = mnew;
            lrun *= sc;
#pragma unroll
            for (int c = 0; c < 4; c++)
#pragma unroll
                for (int j = 0; j < 4; j++) acc[c][j] *= sc;
        }

        u16* pw = Ps[w];
        float rc[4];
#pragma unroll
        for (int c = 0; c < 4; c++) {
            float p0 = exp2f(st[c][0] - mrun);
            float p1 = exp2f(st[c][1] - mrun);
            float p2 = exp2f(st[c][2] - mrun);
            float p3 = exp2f(st[c][3] - mrun);
            rc[c] = (p0 + p1) + (p2 + p3);
            u32x2 pk;
            pk[0] = pk2bf(p0, p1);
            pk[1] = pk2bf(p2, p3);
            *(u32x2*)&pw[lr * 64 + ((c * 16 + lg * 4) ^ swz)] = pk;
        }
        lrun += (rc[0] + rc[1]) + (rc[2] + rc[3]);

        const u16* VsC = Vs[cur];
        __builtin_amdgcn_s_setprio(1);
        const short8 pb0 = *(const short8*)&pw[lr * 64 + ((lg * 8) ^ swz)];
        const short8 pb1 = *(const short8*)&pw[lr * 64 + ((32 | (lg * 8)) ^ swz)];
#pragma unroll
        for (int c = 0; c < 4; c++) {
            const short8 vb0 = *(const short8*)&VsC[(c * 16 + lr) * 64 + ((lg * 8) ^ swz)];
            const short8 vb1 = *(const short8*)&VsC[(c * 16 + lr) * 64 + ((32 | (lg * 8)) ^ swz)];
            acc[c] = __builtin_amdgcn_mfma_f32_16x16x32_bf16(vb0, pb0, acc[c], 0, 0, 0);
            acc[c] = __builtin_amdgcn_mfma_f32_16x16x32_bf16(vb1, pb1, acc[c], 0, 0, 0);
        }
        __builtin_amdgcn_s_setprio(0);

        if (more) {
            *(short8*)&Ks[cur ^ 1][r0 * 64 + sw0] = kr0;
            *(short8*)&Ks[cur ^ 1][r1 * 64 + sw1] = kr1;
            *(short8*)&Vs[cur ^ 1][r0 * 64 + sw0] = vr0;
            *(short8*)&Vs[cur ^ 1][r1 * 64 + sw1] = vr1;
            __syncthreads();
            cur ^= 1;
        }
    }

    {
        float tot = lrun;
        tot += __shfl_xor(tot, 16, 64);
        tot += __shfl_xor(tot, 32, 64);
        float inv = 1.0f / tot;
        int q = q0 + w * 16 + lr;
        size_t yb = (size_t)(b * Tq + q) * 768 + h * 64;
#pragma unroll
        for (int c = 0; c < 4; c++) {
            u32x2 pk;
            pk[0] = pk2bf(acc[c][0] * inv, acc[c][1] * inv);
            pk[1] = pk2bf(acc[c][2] * inv, acc[c][3] * inv);
            *(u32x2*)&Y[yb + c * 16 + lg * 4] = pk;
        }
    }
}

// ---------------- launcher ----------------
extern "C" void kernel_launch(void* const* d_in, const int* in_sizes, int n_in,
                              void* d_out, int out_size, void* d_ws, size_t ws_size,
                              hipStream_t stream)
{
    (void)in_sizes; (void)n_in; (void)out_size; (void)ws_size;
    const float* x    = (const float*)d_in[0];
    const float* enc  = (const float*)d_in[1];
    const float* ln1g = (const float*)d_in[2];
    const float* ln1b = (const float*)d_in[3];
    const float* ln2g = (const float*)d_in[4];
    const float* ln2b = (const float*)d_in[5];
    const float* sWq  = (const float*)d_in[6];
    const float* sbq  = (const float*)d_in[7];
    const float* sWk  = (const float*)d_in[8];
    const float* sbk  = (const float*)d_in[9];
    const float* sWv  = (const float*)d_in[10];
    const float* sbv  = (const float*)d_in[11];
    const float* sWo  = (const float*)d_in[12];
    const float* sbo  = (const float*)d_in[13];
    const float* cWq  = (const float*)d_in[14];
    const float* cbq  = (const float*)d_in[15];
    const float* cWk  = (const float*)d_in[16];
    const float* cbk  = (const float*)d_in[17];
    const float* cWv  = (const float*)d_in[18];
    const float* cbv  = (const float*)d_in[19];
    const float* cWo  = (const float*)d_in[20];
    const float* cbo  = (const float*)d_in[21];
    const float* mW1  = (const float*)d_in[22];
    const float* mb1  = (const float*)d_in[23];
    const float* mW2  = (const float*)d_in[24];
    const float* mb2  = (const float*)d_in[25];
    float* out = (float*)d_out;

    const int Bb = 4, T = 2048, S = 512, C = 768, P = 1024, F = 3072;
    const int M = Bb * T;    // 8192
    const int MS = Bb * S;   // 2048

    char* ws = (char*)d_ws;
    size_t off = 0;
    auto alloc = [&](size_t bytes) -> void* {
        void* p = ws + off;
        off += (bytes + 255) & ~(size_t)255;
        return p;
    };

    u16* wqkvT = (u16*)alloc((size_t)3 * C * C * 2);
    u16* sWoT  = (u16*)alloc((size_t)C * C * 2);
    u16* cWqT  = (u16*)alloc((size_t)C * C * 2);
    u16* ckvT  = (u16*)alloc((size_t)2 * C * P * 2);
    u16* cWoT  = (u16*)alloc((size_t)C * C * 2);
    u16* mW1T  = (u16*)alloc((size_t)F * C * 2);
    u16* mW2T  = (u16*)alloc((size_t)C * F * 2);
    u16* encbf = (u16*)alloc((size_t)MS * P * 2);
    float* slotA = (float*)alloc((size_t)M * C * 4);   // x2
    u16*   slotC = (u16*)alloc((size_t)M * C * 2);     // xbf (bf16 activation stream)
    u16*   big   = (u16*)alloc((size_t)M * F * 2);

    u16* qbf = big;
    u16* kbf = big + (size_t)M * C;
    u16* vbf = big + (size_t)2 * M * C;
    u16* ybf = big + (size_t)3 * M * C;
    u16* midbf = big;

    float* x2 = slotA;
    u16* xbf = slotC;

    PrepArgs pa;
    const float* srcs[11] = { sWq, sWk, sWv, sWo, cWq, cWk, cWv, cWo, mW1, mW2, enc };
    u16* dsts[11] = { wqkvT, wqkvT + (size_t)C * C, wqkvT + (size_t)2 * C * C,
                      sWoT, cWqT, ckvT, ckvT + (size_t)C * P, cWoT, mW1T, mW2T, encbf };
    int Ks_[11] = { C, C, C, C, C, P, P, C, C, F, 0 };
    int Ns_[11] = { C, C, C, C, C, C, C, C, F, C, MS * P };
    int cum = 0;
    for (int i = 0; i < 11; i++) {
        pa.src[i] = srcs[i]; pa.dst[i] = dsts[i]; pa.K[i] = Ks_[i]; pa.N[i] = Ns_[i];
        int nb = Ks_[i] ? (Ns_[i] / 32) * (Ks_[i] / 32) : (Ns_[i] / 2048);
        cum += nb; pa.end[i] = cum;
    }
    pa.cnt = 11;
    k_prep<<<cum, dim3(32, 8), 0, stream>>>(pa);

    // LN1: bf16 output only
    k_layernorm<<<M, 256, 0, stream>>>(x, ln1g, ln1b, nullptr, xbf);

    // QKV fused: N = 2304, BN=192, grid 12x64
    k_gemm<192><<<dim3(12, 64), 256, 0, stream>>>(
        xbf, wqkvT, sbq, sbk, sbv, nullptr, nullptr, nullptr, qbf, kbf, vbf, M, 2304, C, 0, 2, 11);

    k_attn<true><<<dim3(Bb * 12, T / 64), 256, 0, stream>>>(qbf, kbf, vbf, ybf, T, T);

    // attn out: residB = xbf (LN1 bf16), write xbf in place
    k_gemm<64><<<dim3(12, 64), 256, 0, stream>>>(
        ybf, sWoT, sbo, nullptr, nullptr, nullptr, xbf, nullptr, xbf, nullptr, nullptr, M, C, C, 0, 0, 0);

    // cross Q (A = xbf holding x1 in bf16)
    k_gemm<64><<<dim3(12, 64), 256, 0, stream>>>(
        xbf, cWqT, cbq, nullptr, nullptr, nullptr, nullptr, nullptr, qbf, nullptr, nullptr, M, C, C, 0, 0, 0);

    // cross K/V fused: N=1536, K=1024, M=2048
    k_gemm<64><<<dim3(24, 16), 256, 0, stream>>>(
        encbf, ckvT, cbk, nullptr, cbv, nullptr, nullptr, nullptr, kbf, nullptr, vbf, MS, 1536, P, 0, 3, 9);

    k_attn<false><<<dim3(Bb * 12, T / 64), 256, 0, stream>>>(qbf, kbf, vbf, ybf, T, S);

    // cross out: residB = xbf (x1 bf16) -> x2 (f32)
    k_gemm<64><<<dim3(12, 64), 256, 0, stream>>>(
        ybf, cWoT, cbo, nullptr, nullptr, nullptr, xbf, x2, nullptr, nullptr, nullptr, M, C, C, 0, 0, 0);

    k_layernorm<<<M, 256, 0, stream>>>(x2, ln2g, ln2b, nullptr, xbf);

    // MLP1: N=3072, BN=192, grid 16x64, gelu
    k_gemm<192><<<dim3(16, 64), 256, 0, stream>>>(
        xbf, mW1T, mb1, nullptr, nullptr, nullptr, nullptr, nullptr, midbf, nullptr, nullptr, M, F, C, 1, 0, 0);

    // MLP2: N=768, K=3072, resid=x2 (f32) -> out (f32)
    k_gemm<64><<<dim3(12, 64), 256, 0, stream>>>(
        midbf, mW2T, mb2, nullptr, nullptr, x2, nullptr, out, nullptr, nullptr, nullptr, M, C, F, 0, 0, 0);
}

// Round 19
// 403.761 us; speedup vs baseline: 1.0176x; 1.0176x over previous
//
#include <hip/hip_runtime.h>
#include <math.h>

typedef unsigned short u16;
typedef unsigned int u32;
typedef __attribute__((ext_vector_type(8))) short short8;
typedef __attribute__((ext_vector_type(2))) unsigned int u32x2;
typedef __attribute__((ext_vector_type(4))) float f32x4;

static __device__ __forceinline__ u16 f2bf(float f) {
    union { float f; unsigned int u; } c; c.f = f;
    unsigned int u = c.u;
    u += 0x7FFF + ((u >> 16) & 1);
    return (u16)(u >> 16);
}
static __device__ __forceinline__ float bf2f(u16 u) {
    union { unsigned int i; float f; } c; c.i = ((unsigned int)u) << 16;
    return c.f;
}
// pack two f32 -> two bf16 in one VALU op
static __device__ __forceinline__ u32 pk2bf(float lo, float hi) {
    u32 r;
    asm("v_cvt_pk_bf16_f32 %0, %1, %2" : "=v"(r) : "v"(lo), "v"(hi));
    return r;
}
// tanh-form GELU via sigmoid
static __device__ __forceinline__ float gelu_f(float v) {
    float y = 0.7978845608f * (v + 0.044715f * v * v * v);
    return v / (1.0f + __expf(-2.0f * y));
}

#define GLOAD16(g, s) __builtin_amdgcn_global_load_lds( \
    (const __attribute__((address_space(1))) void*)(g), \
    (__attribute__((address_space(3))) void*)(s), 16, 0, 0)

// ---------------- merged prep ----------------
struct PrepArgs {
    const float* src[11];
    u16* dst[11];
    int K[11];
    int N[11];
    int end[11];
    int cnt;
};

__global__ void k_prep(PrepArgs a)
{
    __shared__ float tile[32][33];
    const int bid = blockIdx.x;
    int e = 0;
    while (e < a.cnt - 1 && bid >= a.end[e]) e++;
    const int local = bid - (e ? a.end[e - 1] : 0);
    const float* __restrict__ src = a.src[e];
    u16* __restrict__ dst = a.dst[e];
    const int K = a.K[e], N = a.N[e];
    const int tx = threadIdx.x, ty = threadIdx.y;

    if (K == 0) {
        size_t base = (size_t)local * 2048 + (size_t)(ty * 32 + tx) * 8;
        float4 v0 = *(const float4*)(src + base);
        float4 v1 = *(const float4*)(src + base + 4);
        short8 o;
        o[0] = (short)f2bf(v0.x); o[1] = (short)f2bf(v0.y);
        o[2] = (short)f2bf(v0.z); o[3] = (short)f2bf(v0.w);
        o[4] = (short)f2bf(v1.x); o[5] = (short)f2bf(v1.y);
        o[6] = (short)f2bf(v1.z); o[7] = (short)f2bf(v1.w);
        *(short8*)&dst[base] = o;
        return;
    }
    const int nbx = N / 32;
    const int bx = local % nbx, by = local / nbx;
    const int n0 = bx * 32, k0 = by * 32;
#pragma unroll
    for (int i = 0; i < 4; i++)
        tile[ty + i * 8][tx] = src[(size_t)(k0 + ty + i * 8) * N + n0 + tx];
    __syncthreads();
#pragma unroll
    for (int i = 0; i < 4; i++)
        dst[(size_t)(n0 + ty + i * 8) * K + k0 + tx] = f2bf(tile[tx][ty + i * 8]);
}

// ---------------- LayerNorm over 768 ----------------
__global__ __launch_bounds__(256) void k_layernorm(
    const float* __restrict__ x, const float* __restrict__ g, const float* __restrict__ b,
    float* __restrict__ outF, u16* __restrict__ outB)
{
    const int row = blockIdx.x, t = threadIdx.x;
    const float* xr = x + (size_t)row * 768;
    float v[3];
#pragma unroll
    for (int i = 0; i < 3; i++) v[i] = xr[t + i * 256];
    __shared__ float sred[4];
    float s = v[0] + v[1] + v[2];
#pragma unroll
    for (int o = 32; o; o >>= 1) s += __shfl_xor(s, o, 64);
    if ((t & 63) == 0) sred[t >> 6] = s;
    __syncthreads();
    float mu = (sred[0] + sred[1] + sred[2] + sred[3]) * (1.0f / 768.0f);
    __syncthreads();
    float q = 0.f;
#pragma unroll
    for (int i = 0; i < 3; i++) { float d = v[i] - mu; q += d * d; }
#pragma unroll
    for (int o = 32; o; o >>= 1) q += __shfl_xor(q, o, 64);
    if ((t & 63) == 0) sred[t >> 6] = q;
    __syncthreads();
    float var = (sred[0] + sred[1] + sred[2] + sred[3]) * (1.0f / 768.0f);
    float rstd = rsqrtf(var + 1e-5f);
#pragma unroll
    for (int i = 0; i < 3; i++) {
        int c = t + i * 256;
        float y = (v[i] - mu) * rstd * g[c] + b[c];
        if (outF) outF[(size_t)row * 768 + c] = y;
        if (outB) outB[(size_t)row * 768 + c] = f2bf(y);
    }
}

// ---------------- GEMM: BM=128, template<BN>, BK=64, both-sides XOR swizzle, XCD swizzle ----------------
// mode 0 epilogue: + bias, optional gelu, optional f32 resid, optional bf16 resid,
// optional f32 out, optional bf16 out.
template<int BN>
__global__ __launch_bounds__(256) void k_gemm(
    const u16* __restrict__ A, const u16* __restrict__ Bt,
    const float* __restrict__ b1, const float* __restrict__ b2, const float* __restrict__ b3,
    const float* __restrict__ resid, const u16* __restrict__ residB,
    float* __restrict__ outF, u16* __restrict__ outB, u16* __restrict__ outK, u16* __restrict__ outV,
    int M, int N, int K, int do_gelu, int mode, int vT_log)
{
    constexpr int MR = (BN == 128) ? 4 : 2;
    __shared__ u16 As[128 * 64];
    __shared__ u16 Bs[BN * 64];
    const int t = threadIdx.x;
    const int w = t >> 6, l = t & 63;
    const int lr = l & 15, lg = l >> 4;

    const unsigned nwg = gridDim.x * gridDim.y;
    unsigned bid = blockIdx.y * gridDim.x + blockIdx.x;
    bid = (bid & 7) * (nwg >> 3) + (bid >> 3);
    const int m0 = (bid / gridDim.x) * 128, n0 = (bid % gridDim.x) * BN;

    const int wr = (BN == 128) ? ((w >> 1) * 64) : (w * 32);
    const int wc = (BN == 128) ? ((w & 1) * 64) : 0;

    const int srow = t >> 3;            // 0..31
    const int sslot = t & 7;            // 16B slot within 128B row

    f32x4 acc[MR][4] = {};

    for (int k0 = 0; k0 < K; k0 += 64) {
        __syncthreads();
#pragma unroll
        for (int i = 0; i < 4; i++) {
            int row = i * 32 + srow;
            GLOAD16(A + (size_t)(m0 + row) * K + k0 + ((sslot ^ (row & 7)) * 8),
                    &As[i * 2048 + w * 512]);
        }
#pragma unroll
        for (int i = 0; i < BN / 32; i++) {
            int row = i * 32 + srow;
            GLOAD16(Bt + (size_t)(n0 + row) * K + k0 + ((sslot ^ (row & 7)) * 8),
                    &Bs[i * 2048 + w * 512]);
        }
        __syncthreads();
#pragma unroll
        for (int kk = 0; kk < 2; kk++) {
            const int ce = kk * 32 + lg * 8;
            short8 af[MR], bfr[4];
#pragma unroll
            for (int m = 0; m < MR; m++) {
                int row = wr + m * 16 + lr;
                af[m] = *(const short8*)&As[row * 64 + (ce ^ ((row & 7) << 3))];
            }
#pragma unroll
            for (int n = 0; n < 4; n++) {
                int row = wc + n * 16 + lr;
                bfr[n] = *(const short8*)&Bs[row * 64 + (ce ^ ((row & 7) << 3))];
            }
#pragma unroll
            for (int m = 0; m < MR; m++)
#pragma unroll
                for (int n = 0; n < 4; n++)
                    acc[m][n] = __builtin_amdgcn_mfma_f32_16x16x32_bf16(af[m], bfr[n], acc[m][n], 0, 0, 0);
        }
    }

#pragma unroll
    for (int m = 0; m < MR; m++) {
        int row0 = m0 + wr + m * 16 + lg * 4;
#pragma unroll
        for (int n = 0; n < 4; n++) {
            int col = n0 + wc + n * 16 + lr;
            const float* bp = b1; int lc = col; u16* tgt = outB; int vT = 0;
            if (mode == 2) {
                if (col >= 1536)     { bp = b3; lc = col - 1536; tgt = outV; vT = 1; }
                else if (col >= 768) { bp = b2; lc = col - 768;  tgt = outK; }
            } else if (mode == 3) {
                if (col >= 768)      { bp = b3; lc = col - 768;  tgt = outV; vT = 1; }
            }
            float bv = bp[lc];
            float vv[4];
#pragma unroll
            for (int j = 0; j < 4; j++) {
                float v = acc[m][n][j] + bv;
                if (do_gelu) v = gelu_f(v);
                vv[j] = v;
            }
            if (mode == 0) {
#pragma unroll
                for (int j = 0; j < 4; j++) {
                    size_t idx = (size_t)(row0 + j) * N + col;
                    float v = vv[j];
                    if (resid)  v += resid[idx];
                    if (residB) v += bf2f(residB[idx]);
                    if (outF) outF[idx] = v;
                    if (outB) outB[idx] = f2bf(v);
                }
            } else if (!vT) {
#pragma unroll
                for (int j = 0; j < 4; j++)
                    tgt[(size_t)(row0 + j) * 768 + lc] = f2bf(vv[j]);
            } else {
                int head = lc >> 6, d = lc & 63;
                int bq = row0 >> vT_log, s = row0 & ((1 << vT_log) - 1);
                u32x2 pk;
                pk[0] = pk2bf(vv[0], vv[1]);
                pk[1] = pk2bf(vv[2], vv[3]);
                *(u32x2*)&tgt[((size_t)((bq * 12 + head) * 64 + d) << vT_log) + s] = pk;
            }
        }
    }
}

// ---------------- Flash attention: QBLK=64 (4 waves x 16 q-rows), swapped-operand ----------------
template<bool CAUSAL>
__global__ __launch_bounds__(256) void k_attn(
    const u16* __restrict__ Q, const u16* __restrict__ K,
    const u16* __restrict__ Vt, u16* __restrict__ Y,
    int Tq, int Skv)
{
    const int bh = blockIdx.x;
    const int b = bh / 12, h = bh % 12;
    const int qt = CAUSAL ? ((int)gridDim.y - 1 - (int)blockIdx.y) : blockIdx.y;
    const int q0 = qt * 64;
    const int t = threadIdx.x, w = t >> 6, l = t & 63;
    const int lr = l & 15, lg = l >> 4;
    const int swz = (lr & 7) << 3;
    const float QSC = 0.125f * 1.44269504088896f;

    const u16* Qb = Q + (size_t)b * Tq * 768 + h * 64;
    const u16* Kb = K + (size_t)b * Skv * 768 + h * 64;
    const u16* Vb = Vt + (size_t)bh * 64 * Skv;

    __shared__ u16 Ks[2][64 * 64];
    __shared__ u16 Vs[2][64 * 64];
    __shared__ u16 Ps[4][16 * 64];

    short8 aq[2];
    {
        const u16* qr = Qb + (size_t)(q0 + w * 16 + lr) * 768 + lg * 8;
#pragma unroll
        for (int hh = 0; hh < 2; hh++) {
            short8 raw = *(const short8*)(qr + hh * 32);
            union { short8 s; u32 u[4]; } cv;
#pragma unroll
            for (int i = 0; i < 4; i++)
                cv.u[i] = pk2bf(bf2f((u16)raw[2 * i]) * QSC, bf2f((u16)raw[2 * i + 1]) * QSC);
            aq[hh] = cv.s;
        }
    }

    f32x4 acc[4] = {};
    float mrun = -INFINITY;
    float lrun = 0.f;

    const int nt = CAUSAL ? (qt + 1) : (Skv / 64);

    const int r0 = t >> 3, r1 = 32 + (t >> 3);
    const int db = (t & 7) * 8;
    const int sw0 = db ^ ((r0 & 7) << 3);
    const int sw1 = db ^ ((r1 & 7) << 3);

    short8 kr0, kr1, vr0, vr1;
    kr0 = *(const short8*)(Kb + (size_t)r0 * 768 + db);
    kr1 = *(const short8*)(Kb + (size_t)r1 * 768 + db);
    vr0 = *(const short8*)(Vb + (size_t)r0 * Skv + db);
    vr1 = *(const short8*)(Vb + (size_t)r1 * Skv + db);
    *(short8*)&Ks[0][r0 * 64 + sw0] = kr0;
    *(short8*)&Ks[0][r1 * 64 + sw1] = kr1;
    *(short8*)&Vs[0][r0 * 64 + sw0] = vr0;
    *(short8*)&Vs[0][r1 * 64 + sw1] = vr1;
    __syncthreads();
    int cur = 0;

    for (int kt = 0; kt < nt; kt++) {
        const int kv0 = kt * 64;
        const bool more = (kt + 1 < nt);
        if (more) {
            const int kn = kv0 + 64;
            kr0 = *(const short8*)(Kb + (size_t)(kn + r0) * 768 + db);
            kr1 = *(const short8*)(Kb + (size_t)(kn + r1) * 768 + db);
            vr0 = *(const short8*)(Vb + (size_t)r0 * Skv + kn + db);
            vr1 = *(const short8*)(Vb + (size_t)r1 * Skv + kn + db);
        }

        const u16* KsC = Ks[cur];
        f32x4 st[4];
        __builtin_amdgcn_s_setprio(1);
#pragma unroll
        for (int c = 0; c < 4; c++) {
            const short8 kb0 = *(const short8*)&KsC[(c * 16 + lr) * 64 + ((lg * 8) ^ swz)];
            const short8 kb1 = *(const short8*)&KsC[(c * 16 + lr) * 64 + ((32 | (lg * 8)) ^ swz)];
            f32x4 a = {};
            a = __builtin_amdgcn_mfma_f32_16x16x32_bf16(kb0, aq[0], a, 0, 0, 0);
            a = __builtin_amdgcn_mfma_f32_16x16x32_bf16(kb1, aq[1], a, 0, 0, 0);
            st[c] = a;
        }
        __builtin_amdgcn_s_setprio(0);

        if (CAUSAL && kt == nt - 1) {
            int qv = q0 + w * 16 + lr;
#pragma unroll
            for (int c = 0; c < 4; c++)
#pragma unroll
                for (int j = 0; j < 4; j++) {
                    int kvv = kv0 + c * 16 + lg * 4 + j;
                    if (kvv > qv) st[c][j] = -1e30f;
                }
        }

        float mc[4];
#pragma unroll
        for (int c = 0; c < 4; c++)
            mc[c] = fmaxf(fmaxf(st[c][0], st[c][1]), fmaxf(st[c][2], st[c][3]));
        float lmax = fmaxf(fmaxf(mc[0], mc[1]), fmaxf(mc[2], mc[3]));
        if (!__all(lmax - mrun <= 8.0f)) {
            float m = lmax;
            m = fmaxf(m, __shfl_xor(m, 16, 64));
            m = fmaxf(m, __shfl_xor(m, 32, 64));
            float mnew = fmaxf(mrun, m);
            float sc = exp2f(mrun - mnew);
            mrun = mnew;
            lrun *= sc;
#pragma unroll
            for (int c = 0; c < 4; c++)
#pragma unroll
                for (int j = 0; j < 4; j++) acc[c][j] *= sc;
        }

        u16* pw = Ps[w];
        float rc[4];
#pragma unroll
        for (int c = 0; c < 4; c++) {
            float p0 = exp2f(st[c][0] - mrun);
            float p1 = exp2f(st[c][1] - mrun);
            float p2 = exp2f(st[c][2] - mrun);
            float p3 = exp2f(st[c][3] - mrun);
            rc[c] = (p0 + p1) + (p2 + p3);
            u32x2 pk;
            pk[0] = pk2bf(p0, p1);
            pk[1] = pk2bf(p2, p3);
            *(u32x2*)&pw[lr * 64 + ((c * 16 + lg * 4) ^ swz)] = pk;
        }
        lrun += (rc[0] + rc[1]) + (rc[2] + rc[3]);

        const u16* VsC = Vs[cur];
        __builtin_amdgcn_s_setprio(1);
        const short8 pb0 = *(const short8*)&pw[lr * 64 + ((lg * 8) ^ swz)];
        const short8 pb1 = *(const short8*)&pw[lr * 64 + ((32 | (lg * 8)) ^ swz)];
#pragma unroll
        for (int c = 0; c < 4; c++) {
            const short8 vb0 = *(const short8*)&VsC[(c * 16 + lr) * 64 + ((lg * 8) ^ swz)];
            const short8 vb1 = *(const short8*)&VsC[(c * 16 + lr) * 64 + ((32 | (lg * 8)) ^ swz)];
            acc[c] = __builtin_amdgcn_mfma_f32_16x16x32_bf16(vb0, pb0, acc[c], 0, 0, 0);
            acc[c] = __builtin_amdgcn_mfma_f32_16x16x32_bf16(vb1, pb1, acc[c], 0, 0, 0);
        }
        __builtin_amdgcn_s_setprio(0);

        if (more) {
            *(short8*)&Ks[cur ^ 1][r0 * 64 + sw0] = kr0;
            *(short8*)&Ks[cur ^ 1][r1 * 64 + sw1] = kr1;
            *(short8*)&Vs[cur ^ 1][r0 * 64 + sw0] = vr0;
            *(short8*)&Vs[cur ^ 1][r1 * 64 + sw1] = vr1;
            __syncthreads();
            cur ^= 1;
        }
    }

    {
        float tot = lrun;
        tot += __shfl_xor(tot, 16, 64);
        tot += __shfl_xor(tot, 32, 64);
        float inv = 1.0f / tot;
        int q = q0 + w * 16 + lr;
        size_t yb = (size_t)(b * Tq + q) * 768 + h * 64;
#pragma unroll
        for (int c = 0; c < 4; c++) {
            u32x2 pk;
            pk[0] = pk2bf(acc[c][0] * inv, acc[c][1] * inv);
            pk[1] = pk2bf(acc[c][2] * inv, acc[c][3] * inv);
            *(u32x2*)&Y[yb + c * 16 + lg * 4] = pk;
        }
    }
}

// ---------------- launcher ----------------
extern "C" void kernel_launch(void* const* d_in, const int* in_sizes, int n_in,
                              void* d_out, int out_size, void* d_ws, size_t ws_size,
                              hipStream_t stream)
{
    (void)in_sizes; (void)n_in; (void)out_size; (void)ws_size;
    const float* x    = (const float*)d_in[0];
    const float* enc  = (const float*)d_in[1];
    const float* ln1g = (const float*)d_in[2];
    const float* ln1b = (const float*)d_in[3];
    const float* ln2g = (const float*)d_in[4];
    const float* ln2b = (const float*)d_in[5];
    const float* sWq  = (const float*)d_in[6];
    const float* sbq  = (const float*)d_in[7];
    const float* sWk  = (const float*)d_in[8];
    const float* sbk  = (const float*)d_in[9];
    const float* sWv  = (const float*)d_in[10];
    const float* sbv  = (const float*)d_in[11];
    const float* sWo  = (const float*)d_in[12];
    const float* sbo  = (const float*)d_in[13];
    const float* cWq  = (const float*)d_in[14];
    const float* cbq  = (const float*)d_in[15];
    const float* cWk  = (const float*)d_in[16];
    const float* cbk  = (const float*)d_in[17];
    const float* cWv  = (const float*)d_in[18];
    const float* cbv  = (const float*)d_in[19];
    const float* cWo  = (const float*)d_in[20];
    const float* cbo  = (const float*)d_in[21];
    const float* mW1  = (const float*)d_in[22];
    const float* mb1  = (const float*)d_in[23];
    const float* mW2  = (const float*)d_in[24];
    const float* mb2  = (const float*)d_in[25];
    float* out = (float*)d_out;

    const int Bb = 4, T = 2048, S = 512, C = 768, P = 1024, F = 3072;
    const int M = Bb * T;    // 8192
    const int MS = Bb * S;   // 2048

    char* ws = (char*)d_ws;
    size_t off = 0;
    auto alloc = [&](size_t bytes) -> void* {
        void* p = ws + off;
        off += (bytes + 255) & ~(size_t)255;
        return p;
    };

    u16* wqkvT = (u16*)alloc((size_t)3 * C * C * 2);
    u16* sWoT  = (u16*)alloc((size_t)C * C * 2);
    u16* cWqT  = (u16*)alloc((size_t)C * C * 2);
    u16* ckvT  = (u16*)alloc((size_t)2 * C * P * 2);
    u16* cWoT  = (u16*)alloc((size_t)C * C * 2);
    u16* mW1T  = (u16*)alloc((size_t)F * C * 2);
    u16* mW2T  = (u16*)alloc((size_t)C * F * 2);
    u16* encbf = (u16*)alloc((size_t)MS * P * 2);
    float* slotA = (float*)alloc((size_t)M * C * 4);   // x2
    u16*   slotC = (u16*)alloc((size_t)M * C * 2);     // xbf (bf16 activation stream)
    u16*   big   = (u16*)alloc((size_t)M * F * 2);

    u16* qbf = big;
    u16* kbf = big + (size_t)M * C;
    u16* vbf = big + (size_t)2 * M * C;
    u16* ybf = big + (size_t)3 * M * C;
    u16* midbf = big;

    float* x2 = slotA;
    u16* xbf = slotC;

    PrepArgs pa;
    const float* srcs[11] = { sWq, sWk, sWv, sWo, cWq, cWk, cWv, cWo, mW1, mW2, enc };
    u16* dsts[11] = { wqkvT, wqkvT + (size_t)C * C, wqkvT + (size_t)2 * C * C,
                      sWoT, cWqT, ckvT, ckvT + (size_t)C * P, cWoT, mW1T, mW2T, encbf };
    int Ks_[11] = { C, C, C, C, C, P, P, C, C, F, 0 };
    int Ns_[11] = { C, C, C, C, C, C, C, C, F, C, MS * P };
    int cum = 0;
    for (int i = 0; i < 11; i++) {
        pa.src[i] = srcs[i]; pa.dst[i] = dsts[i]; pa.K[i] = Ks_[i]; pa.N[i] = Ns_[i];
        int nb = Ks_[i] ? (Ns_[i] / 32) * (Ks_[i] / 32) : (Ns_[i] / 2048);
        cum += nb; pa.end[i] = cum;
    }
    pa.cnt = 11;
    k_prep<<<cum, dim3(32, 8), 0, stream>>>(pa);

    // LN1: bf16 output only (the f32 copy was only ever read as a residual)
    k_layernorm<<<M, 256, 0, stream>>>(x, ln1g, ln1b, nullptr, xbf);

    // QKV fused: N = 2304
    k_gemm<128><<<dim3(18, 64), 256, 0, stream>>>(
        xbf, wqkvT, sbq, sbk, sbv, nullptr, nullptr, nullptr, qbf, kbf, vbf, M, 2304, C, 0, 2, 11);

    k_attn<true><<<dim3(Bb * 12, T / 64), 256, 0, stream>>>(qbf, kbf, vbf, ybf, T, T);

    // attn out: residB = xbf (LN1 bf16), write xbf in place (same-index, thread-local)
    k_gemm<64><<<dim3(12, 64), 256, 0, stream>>>(
        ybf, sWoT, sbo, nullptr, nullptr, nullptr, xbf, nullptr, xbf, nullptr, nullptr, M, C, C, 0, 0, 0);

    // cross Q (A = xbf, now holding x1 in bf16)
    k_gemm<64><<<dim3(12, 64), 256, 0, stream>>>(
        xbf, cWqT, cbq, nullptr, nullptr, nullptr, nullptr, nullptr, qbf, nullptr, nullptr, M, C, C, 0, 0, 0);

    // cross K/V fused: N=1536, K=1024, M=2048
    k_gemm<64><<<dim3(24, 16), 256, 0, stream>>>(
        encbf, ckvT, cbk, nullptr, cbv, nullptr, nullptr, nullptr, kbf, nullptr, vbf, MS, 1536, P, 0, 3, 9);

    k_attn<false><<<dim3(Bb * 12, T / 64), 256, 0, stream>>>(qbf, kbf, vbf, ybf, T, S);

    // cross out: residB = xbf (x1 bf16) -> x2 (f32, kept full precision for final residual)
    k_gemm<64><<<dim3(12, 64), 256, 0, stream>>>(
        ybf, cWoT, cbo, nullptr, nullptr, nullptr, xbf, x2, nullptr, nullptr, nullptr, M, C, C, 0, 0, 0);

    k_layernorm<<<M, 256, 0, stream>>>(x2, ln2g, ln2b, nullptr, xbf);

    // MLP1: N=3072, gelu
    k_gemm<128><<<dim3(24, 64), 256, 0, stream>>>(
        xbf, mW1T, mb1, nullptr, nullptr, nullptr, nullptr, nullptr, midbf, nullptr, nullptr, M, F, C, 1, 0, 0);

    // MLP2: N=768, K=3072, resid=x2 (f32) -> out (f32)
    k_gemm<64><<<dim3(12, 64), 256, 0, stream>>>(
        midbf, mW2T, mb2, nullptr, nullptr, x2, nullptr, out, nullptr, nullptr, nullptr, M, C, F, 0, 0, 0);
}